// Round 14
// baseline (149.856 us; speedup 1.0000x reference)
//
#include <hip/hip_runtime.h>

#define T_   16
#define B_   8
#define N_   8
#define H_   128
#define C_   32
#define HW_  256
#define TAR_ 145
#define G4H  512
#define MEMIN 8593
#define AK   8512   // padded K (multiple of 64)
#define XGN  524288
#define KSTEP 64

typedef __attribute__((ext_vector_type(8))) short short8v;
typedef __attribute__((ext_vector_type(4))) float f32x4;
typedef __attribute__((ext_vector_type(4), aligned(4))) float f32x4u;

__device__ __forceinline__ float bf2f(unsigned short u){
  return __uint_as_float(((unsigned int)u) << 16);
}
__device__ __forceinline__ unsigned short f2bf(float x){
  unsigned int b = __float_as_uint(x);
  return (unsigned short)((b + 0x7fffu + ((b >> 16) & 1u)) >> 16);
}
__device__ __forceinline__ unsigned pkbf(float lo, float hi){
  return __builtin_amdgcn_perm(__float_as_uint(hi) + 0x8000u,
                               __float_as_uint(lo) + 0x8000u, 0x07060302u);
}
__device__ __forceinline__ float bflo(unsigned w){ return __uint_as_float(w << 16); }
__device__ __forceinline__ float bfhi(unsigned w){ return __uint_as_float(w & 0xffff0000u); }
__device__ __forceinline__ float sigf(float x){ return 1.f/(1.f + expf(-x)); }

__device__ __forceinline__ void gl_lds16(const void* g, void* l){
  __builtin_amdgcn_global_load_lds(
      (const __attribute__((address_space(1))) unsigned int*)g,
      (__attribute__((address_space(3))) unsigned int*)l, 16, 0, 0);
}
__device__ __forceinline__ void gl_lds4(const void* g, void* l){
  __builtin_amdgcn_global_load_lds(
      (const __attribute__((address_space(1))) unsigned int*)g,
      (__attribute__((address_space(3))) unsigned int*)l, 4, 0, 0);
}

// ---------------------------------------------------------------------------
// shared[h] = Wo_b[h] + sum_d Wv_b[d] * Wo_w[h,d]   (attention collapses)
// ---------------------------------------------------------------------------
__global__ void k_shared(const float* __restrict__ WvB, const float* __restrict__ WoW,
                         const float* __restrict__ WoB, float* __restrict__ sh){
  const int h = blockIdx.x, lane = threadIdx.x;
  float acc = 0.f;
  for(int d = lane; d < 896; d += 64) acc += WvB[d] * WoW[h*896 + d];
  for(int s = 32; s; s >>= 1) acc += __shfl_down(acc, s);
  if(lane == 0) sh[h] = acc + WoB[h];
}

// ---------------------------------------------------------------------------
// gate[tb,n,c] = sigmoid(td_b[n,c] + sum_{x<145} tar[tb,x]*td_w[n,c,x])
// ---------------------------------------------------------------------------
__global__ __launch_bounds__(256) void k_gate(const float* __restrict__ tar,
                                              const float* __restrict__ tdw,
                                              const float* __restrict__ tdb,
                                              float* __restrict__ gate){
  __shared__ float twS[32*145];
  __shared__ float taS[16*145];
  const int tb0 = blockIdx.x * 16, n = blockIdx.y, tid = threadIdx.x;
  for(int i = tid; i < 32*145; i += 256){
    int c = i / 145, x = i - c*145;
    twS[i] = tdw[(n*32 + c)*273 + x];
  }
  for(int i = tid; i < 16*145; i += 256)
    taS[i] = tar[tb0*145 + i];
  __syncthreads();
  for(int o = tid; o < 512; o += 256){
    int r = o >> 5, c = o & 31;
    float a = tdb[n*32 + c];
    const float* tr = &taS[r*145];
    const float* tw = &twS[c*145];
    for(int x = 0; x < 145; ++x) a += tr[x]*tw[x];
    gate[((tb0 + r)*N_ + n)*C_ + c] = 1.f/(1.f + expf(-a));
  }
}

// ---------------------------------------------------------------------------
// conv v2: grid (tb=128, n=8), 256 threads = hw.  Tail covers [8192..8512).
// ---------------------------------------------------------------------------
__global__ __launch_bounds__(256) void k_conv2(
    const float* __restrict__ img, const float* __restrict__ gate,
    const float* __restrict__ cw, const float* __restrict__ cb,
    const float* __restrict__ sh, const float* __restrict__ tar,
    unsigned short* __restrict__ mem)
{
  __shared__ float imgS[8192];    // [c][hw]
  __shared__ float cwgT[1024];    // [c][d] = cw[d][c]*gate[n][c]
  const int tb = blockIdx.x, n = blockIdx.y;
  const int hw = threadIdx.x;
  for(int i = hw; i < 8192; i += 256)
    imgS[i] = img[(size_t)tb*8192 + i];
  for(int i = hw; i < 1024; i += 256){
    const int c = i >> 5, d = i & 31;
    cwgT[i] = cw[d*32 + c] * gate[(tb*8 + n)*32 + c];
  }
  __syncthreads();
  f32x4 acc[8];
  #pragma unroll
  for(int dq = 0; dq < 8; ++dq){
    const f32x4u cv = *(const f32x4u*)&cb[dq*4];
    acc[dq].x = cv.x; acc[dq].y = cv.y; acc[dq].z = cv.z; acc[dq].w = cv.w;
  }
  #pragma unroll 4
  for(int c = 0; c < 32; ++c){
    const float iv = imgS[c*256 + hw];
    #pragma unroll
    for(int dq = 0; dq < 8; ++dq){
      const f32x4 w = *(const f32x4*)&cwgT[c*32 + dq*4];
      acc[dq].x += iv*w.x; acc[dq].y += iv*w.y;
      acc[dq].z += iv*w.z; acc[dq].w += iv*w.w;
    }
  }
  unsigned short* mrow = mem + (size_t)(n*128 + tb)*AK;
  #pragma unroll
  for(int dq = 0; dq < 8; ++dq){
    mrow[(dq*4 + 0)*256 + hw] = f2bf(acc[dq].x);
    mrow[(dq*4 + 1)*256 + hw] = f2bf(acc[dq].y);
    mrow[(dq*4 + 2)*256 + hw] = f2bf(acc[dq].z);
    mrow[(dq*4 + 3)*256 + hw] = f2bf(acc[dq].w);
  }
  for(int i = hw; i < 320; i += 256){
    if(i < 128)      mrow[8192 + i]       = f2bf(sh[i]);
    else if(i < 273) mrow[8320 + i - 128] = f2bf(tar[tb*TAR_ + i - 128]);
    else             mrow[8465 + i - 273] = 0;   // zeros to 8512
  }
}

// ---------------------------------------------------------------------------
// MFMA GEMM v9: one-shot LINEAR-BURST B fill into LDS, then Wih-free K-loop.
// Grid (n=8 [x-major -> XCD-pinned], 32 gt, 4 ks) = 1024 blocks.
// FIX (r14): gt spans 32 tiles (was 8 -> columns 128..511 never computed,
// round-13 absmax 0.2969 = poison-fed LSTM).
// Phase 1: block reads its 16 Wih row-segments as linear ~8.5KB bursts
//   (256 consecutive threads sweep one row = fill/copy pattern), converts
//   f32->bf16 (pkbf), writes 68KB LDS panel w/ verified chunk-XOR swizzle.
// Phase 2: verified gemm5 skeleton; A ring-2 DMA + counted vmcnt(4);
//   B frags straight from LDS (bf16, no per-step pack).
// C/D: col=lane&15, row=(lane>>4)*4+j.
// ---------------------------------------------------------------------------
__global__ __launch_bounds__(256) void k_gemm9(
    const unsigned short* __restrict__ mem, const float* __restrict__ Wih,
    float* __restrict__ xg4)
{
  extern __shared__ char smem9[];
  unsigned short* Blds = (unsigned short*)smem9;                 // 16*272*16B = 69632
  unsigned short (*Abuf)[8192] = (unsigned short(*)[8192])(smem9 + 69632); // 2x16KB
  const int n = blockIdx.x, gt = blockIdx.y, ks = blockIdx.z;
  const int tid = threadIdx.x;
  const int wv = tid >> 6, ln = tid & 63;
  const int lr = ln & 15, lg = ln >> 4;
  const int g0 = gt*16;
  const int kbeg = (ks == 0) ? 0 : 2176 + (ks - 1)*2112;
  const int nsteps = (ks == 0) ? 34 : 33;
  const int nc = nsteps*8;                  // 272 or 264 chunks (16B) per row
  const unsigned short* An = mem + (size_t)n*128*AK;
  const float* Bn = Wih + (size_t)(n*G4H + g0)*MEMIN + kbeg;

  // ---- Phase 1: linear-burst fill (row-major sweep; each iteration the
  //      block reads one ~8KB contiguous run of a single Wih row).
  const int tot = 16*nc;
  #pragma unroll 4
  for(int j0 = 0; j0 < tot; j0 += 256){
    const int j = j0 + tid;
    if(j < tot){
      const int r = j / nc, c = j - r*nc;
      const float* src = Bn + (size_t)r*MEMIN + c*8;
      const f32x4u v0 = *(const f32x4u*)src;
      const f32x4u v1 = *(const f32x4u*)(src + 4);
      uint4 o;
      o.x = pkbf(v0.x, v0.y); o.y = pkbf(v0.z, v0.w);
      o.z = pkbf(v1.x, v1.y); o.w = pkbf(v1.z, v1.w);
      const int csw = (c & ~7) | ((c & 7) ^ (r & 7));
      *(uint4*)((char*)Blds + r*4352 + csw*16) = o;
    }
  }
  __syncthreads();

#define STAGEA(bb, kk) do{                                                     \
    _Pragma("unroll")                                                          \
    for(int i_ = 0; i_ < 4; ++i_){                                             \
      const int ci_ = i_*256 + tid;                                            \
      const int row_ = ci_ >> 3;                                               \
      gl_lds16(An + (size_t)row_*AK + (kk) + (((ci_ & 7) ^ (row_ & 7)) << 3),  \
               (char*)&Abuf[bb][0] + (i_*256 + wv*64)*16);                     \
    }                                                                          \
  }while(0)

  f32x4 acc0 = {0.f,0.f,0.f,0.f};
  f32x4 acc1 = {0.f,0.f,0.f,0.f};

  STAGEA(0, kbeg);
  if(nsteps > 1) STAGEA(1, kbeg + KSTEP);

  int b = 0;
  for(int t = 0; t < nsteps; ++t){
    if(t < nsteps - 1){
      asm volatile("s_waitcnt vmcnt(4)" ::: "memory");   // stage t done, t+1 in flight
    } else {
      asm volatile("s_waitcnt vmcnt(0)" ::: "memory");
    }
    __builtin_amdgcn_s_barrier();
    #pragma unroll
    for(int s = 0; s < 2; ++s){
      const int jb = (s*4 + lg) ^ (lr & 7);
      const short8v bf = *(const short8v*)((char*)Blds + lr*4352 + (t*8 + jb)*16);
      const short8v a0 = *(const short8v*)&Abuf[b][(wv*32 + lr)*64 + jb*8];
      const short8v a1 = *(const short8v*)&Abuf[b][(wv*32 + 16 + lr)*64 + jb*8];
      acc0 = __builtin_amdgcn_mfma_f32_16x16x32_bf16(a0, bf, acc0, 0, 0, 0);
      acc1 = __builtin_amdgcn_mfma_f32_16x16x32_bf16(a1, bf, acc1, 0, 0, 0);
    }
    __builtin_amdgcn_s_barrier();
    if(t + 2 < nsteps) STAGEA(b, kbeg + (t + 2)*KSTEP);
    b ^= 1;
  }
#undef STAGEA

  float* dst = xg4 + (size_t)ks*XGN;
  const int c0 = g0 + lr;
  const int r0 = wv*32 + lg*4, r1 = r0 + 16;
  #pragma unroll
  for(int j = 0; j < 4; ++j){
    dst[(size_t)((r0 + j)*8 + n)*G4H + c0] = acc0[j];
    dst[(size_t)((r1 + j)*8 + n)*G4H + c0] = acc1[j];
  }
}

// ---------------------------------------------------------------------------
// LSTM v2: 64 blocks = (b,n) pairs, 512 threads = gate-row g.  nsum = number
// of K-split partial buffers to sum.
// ---------------------------------------------------------------------------
__global__ __launch_bounds__(512) void k_lstm2(
    const float* __restrict__ xg4, int nsum, const float* __restrict__ Whh,
    const float* __restrict__ bih, const float* __restrict__ bhh,
    float* __restrict__ out)
{
  __shared__ float hS[128];
  __shared__ float preS[512];
  const int bn = blockIdx.x;
  const int n = bn & 7, b = bn >> 3;
  const int g = threadIdx.x;

  unsigned wr[64];
  const float* wrow = Whh + (size_t)(n*G4H + g)*H_;
  #pragma unroll
  for(int i = 0; i < 32; ++i){
    const f32x4 w = *(const f32x4*)(wrow + i*4);
    wr[2*i]   = pkbf(w.x, w.y);
    wr[2*i+1] = pkbf(w.z, w.w);
  }
  const float bias = bih[n*G4H + g] + bhh[n*G4H + g];
  if(g < 128) hS[g] = 0.f;
  float cc = 0.f;
  __syncthreads();

  for(int t = 0; t < 16; ++t){
    const size_t xb = (size_t)((t*8 + b)*8 + n)*G4H + g;
    float acc = bias;
    for(int u = 0; u < nsum; ++u) acc += xg4[xb + (size_t)u*XGN];
    #pragma unroll
    for(int q = 0; q < 32; ++q){
      const f32x4 hv = *(const f32x4*)&hS[q*4];
      const unsigned w0 = wr[2*q], w1 = wr[2*q+1];
      acc += hv.x*bflo(w0) + hv.y*bfhi(w0) + hv.z*bflo(w1) + hv.w*bfhi(w1);
    }
    preS[g] = acc;
    __syncthreads();
    if(g < 128){
      const float iv = sigf(preS[g]);
      const float fv = sigf(preS[128 + g]);
      const float gv = tanhf(preS[256 + g]);
      const float ov = sigf(preS[384 + g]);
      cc = fv*cc + iv*gv;
      const float hn = ov*tanhf(cc);
      hS[g] = hn;
      out[(t*8 + b)*1024 + n*128 + g] = hn;
      if(t == 15){
        out[131072 + (b*8 + n)*128 + g] = hn;   // hT
        out[139264 + (b*8 + n)*128 + g] = cc;   // cT
      }
    }
    __syncthreads();
  }
}

// ---------------------------------------------------------------------------
// Fallback GEMM (round-9 verified): only used if ws too small for tier A.
// ---------------------------------------------------------------------------
__global__ __launch_bounds__(256) void k_gemm5(
    const unsigned short* __restrict__ mem, const float* __restrict__ Wih,
    float* __restrict__ xg4)
{
  __shared__ unsigned short Abuf[2][128*64];
  __shared__ float          Bbuf[2][16*64];
  const int gt = blockIdx.x, n = blockIdx.y, ks = blockIdx.z;
  const int tid = threadIdx.x;
  const int wv = tid >> 6, ln = tid & 63;
  const int lr = ln & 15, lg = ln >> 4;
  const int g0 = gt*16;
  const int kbeg = (ks == 0) ? 0 : 2176 + (ks - 1)*2112;
  const int nsteps = (ks == 0) ? 34 : 33;
  const unsigned short* An = mem + (size_t)n*128*AK;
  const float* Bn = Wih + (size_t)(n*G4H + g0)*MEMIN;

#define STAGE5(bb, kk) do{                                                     \
    _Pragma("unroll")                                                          \
    for(int i_ = 0; i_ < 4; ++i_){                                             \
      const int ci_ = i_*256 + tid;                                            \
      const int row_ = ci_ >> 3;                                               \
      const unsigned short* src_ = An + (size_t)row_*AK + (kk)                 \
                                   + (((ci_ & 7) ^ (row_ & 7)) << 3);          \
      gl_lds16(src_, &Abuf[bb][(i_*256 + wv*64)*8]);                           \
    }                                                                          \
    _Pragma("unroll")                                                          \
    for(int q_ = 0; q_ < 4; ++q_){                                             \
      const int idx_ = q_*256 + tid;                                           \
      const int g_ = idx_ >> 6;                                                \
      const int kd_ = idx_ & 63;                                               \
      const float* srcB_ = Bn + (size_t)g_*MEMIN + (kk)                        \
                           + ((((kd_ >> 3) ^ (g_ & 7)) << 3) + (kd_ & 7));     \
      gl_lds4(srcB_, &Bbuf[bb][q_*256 + wv*64]);                               \
    }                                                                          \
  }while(0)

  f32x4 acc0 = {0.f,0.f,0.f,0.f};
  f32x4 acc1 = {0.f,0.f,0.f,0.f};

  STAGE5(0, kbeg);
  if(nsteps > 1) STAGE5(1, kbeg + KSTEP);

  int b = 0;
  for(int t = 0; t < nsteps; ++t){
    if(t < nsteps - 1){
      asm volatile("s_waitcnt vmcnt(8)" ::: "memory");
    } else {
      asm volatile("s_waitcnt vmcnt(0)" ::: "memory");
    }
    __builtin_amdgcn_s_barrier();
    #pragma unroll
    for(int s = 0; s < 2; ++s){
      const int jb = (s*4 + lg) ^ (lr & 7);
      const float* bp = &Bbuf[b][lr*64 + jb*8];
      const f32x4 blo = *(const f32x4*)bp;
      const f32x4 bhi = *(const f32x4*)(bp + 4);
      short8v bf;
      unsigned* u = (unsigned*)&bf;
      u[0] = pkbf(blo.x, blo.y); u[1] = pkbf(blo.z, blo.w);
      u[2] = pkbf(bhi.x, bhi.y); u[3] = pkbf(bhi.z, bhi.w);
      const short8v a0 = *(const short8v*)&Abuf[b][(wv*32 + lr)*64 + jb*8];
      const short8v a1 = *(const short8v*)&Abuf[b][(wv*32 + 16 + lr)*64 + jb*8];
      acc0 = __builtin_amdgcn_mfma_f32_16x16x32_bf16(a0, bf, acc0, 0, 0, 0);
      acc1 = __builtin_amdgcn_mfma_f32_16x16x32_bf16(a1, bf, acc1, 0, 0, 0);
    }
    __builtin_amdgcn_s_barrier();
    if(t + 2 < nsteps) STAGE5(b, kbeg + (t+2)*KSTEP);
    b ^= 1;
  }
#undef STAGE5

  float* dst = xg4 + (size_t)ks*XGN;
  const int c0 = g0 + lr;
  const int r0 = wv*32 + lg*4, r1 = r0 + 16;
  #pragma unroll
  for(int j = 0; j < 4; ++j){
    dst[(size_t)((r0 + j)*8 + n)*G4H + c0] = acc0[j];
    dst[(size_t)((r1 + j)*8 + n)*G4H + c0] = acc1[j];
  }
}

// ---------------------------------------------------------------------------
extern "C" void kernel_launch(void* const* d_in, const int* in_sizes, int n_in,
                              void* d_out, int out_size, void* d_ws, size_t ws_size,
                              hipStream_t stream)
{
  (void)in_sizes; (void)n_in; (void)out_size;
  const float* img  = (const float*)d_in[0];
  const float* tar  = (const float*)d_in[1];
  const float* WvB  = (const float*)d_in[7];
  const float* WoW  = (const float*)d_in[8];
  const float* WoB  = (const float*)d_in[9];
  const float* tdw  = (const float*)d_in[10];
  const float* tdb  = (const float*)d_in[11];
  const float* cw   = (const float*)d_in[12];
  const float* cb   = (const float*)d_in[13];
  const float* Wih  = (const float*)d_in[14];
  const float* Whh  = (const float*)d_in[15];
  const float* bih  = (const float*)d_in[16];
  const float* bhh  = (const float*)d_in[17];

  float* wsf   = (float*)d_ws;
  float* gatew = wsf;                       // 32768 f
  float* shw   = wsf + 32768;               // 128 f
  float* xgw   = wsf + 32896;               // 4 x 524288 f
  unsigned short* memA = (unsigned short*)((char*)d_ws + 8520192);   // 17.4 MB
  const size_t WS_7 = 8520192 + (size_t)8*128*AK*2;    // 25,952,768 B (known OK)

  k_shared<<<128, 64, 0, stream>>>(WvB, WoW, WoB, shw);
  k_gate<<<dim3(8, 8), 256, 0, stream>>>(tar, tdw, tdb, gatew);
  k_conv2<<<dim3(128, 8), 256, 0, stream>>>(img, gatew, cw, cb, shw, tar, memA);

  if(ws_size >= WS_7){
    (void)hipFuncSetAttribute((const void*)k_gemm9,
                              hipFuncAttributeMaxDynamicSharedMemorySize, 102400);
    k_gemm9<<<dim3(8, 32, 4), 256, 102400, stream>>>(memA, Wih, xgw);
    k_lstm2<<<64, 512, 0, stream>>>(xgw, 4, Whh, bih, bhh, (float*)d_out);
  } else {
    k_gemm5<<<dim3(32, 8, 4), 256, 0, stream>>>(memA, Wih, xgw);
    k_lstm2<<<64, 512, 0, stream>>>(xgw, 4, Whh, bih, bhh, (float*)d_out);
  }
}

// Round 15
// 117.669 us; speedup vs baseline: 1.2735x; 1.2735x over previous
//
#include <hip/hip_runtime.h>

#define T_   16
#define B_   8
#define N_   8
#define H_   128
#define C_   32
#define HW_  256
#define TAR_ 145
#define G4H  512
#define MEMIN 8593
#define AK   8512   // padded K (multiple of 64)
#define XGN  524288
#define KSTEP 64

typedef __attribute__((ext_vector_type(8))) short short8v;
typedef __attribute__((ext_vector_type(4))) float f32x4;
typedef __attribute__((ext_vector_type(4), aligned(4))) float f32x4u;

__device__ __forceinline__ float bf2f(unsigned short u){
  return __uint_as_float(((unsigned int)u) << 16);
}
__device__ __forceinline__ unsigned short f2bf(float x){
  unsigned int b = __float_as_uint(x);
  return (unsigned short)((b + 0x7fffu + ((b >> 16) & 1u)) >> 16);
}
__device__ __forceinline__ unsigned pkbf(float lo, float hi){
  return __builtin_amdgcn_perm(__float_as_uint(hi) + 0x8000u,
                               __float_as_uint(lo) + 0x8000u, 0x07060302u);
}
__device__ __forceinline__ float bflo(unsigned w){ return __uint_as_float(w << 16); }
__device__ __forceinline__ float bfhi(unsigned w){ return __uint_as_float(w & 0xffff0000u); }
__device__ __forceinline__ float sigf(float x){ return 1.f/(1.f + expf(-x)); }

__device__ __forceinline__ void gl_lds16(const void* g, void* l){
  __builtin_amdgcn_global_load_lds(
      (const __attribute__((address_space(1))) unsigned int*)g,
      (__attribute__((address_space(3))) unsigned int*)l, 16, 0, 0);
}
__device__ __forceinline__ void gl_lds4(const void* g, void* l){
  __builtin_amdgcn_global_load_lds(
      (const __attribute__((address_space(1))) unsigned int*)g,
      (__attribute__((address_space(3))) unsigned int*)l, 4, 0, 0);
}

// ---------------------------------------------------------------------------
// shared[h] = Wo_b[h] + sum_d Wv_b[d] * Wo_w[h,d]   (attention collapses)
// ---------------------------------------------------------------------------
__global__ void k_shared(const float* __restrict__ WvB, const float* __restrict__ WoW,
                         const float* __restrict__ WoB, float* __restrict__ sh){
  const int h = blockIdx.x, lane = threadIdx.x;
  float acc = 0.f;
  for(int d = lane; d < 896; d += 64) acc += WvB[d] * WoW[h*896 + d];
  for(int s = 32; s; s >>= 1) acc += __shfl_down(acc, s);
  if(lane == 0) sh[h] = acc + WoB[h];
}

// ---------------------------------------------------------------------------
// conv v3 (gate fused): 1024 blocks, bid -> n = bid&7 (XCD-pinned: XCD i
// writes mem[n=i] so gemm5x reads it from its own L2), tb = bid>>3.
// gate[c] computed inline (32 threads x 145-dot).  Tail covers [8192..8512).
// ---------------------------------------------------------------------------
__global__ __launch_bounds__(256) void k_conv3(
    const float* __restrict__ img, const float* __restrict__ tar,
    const float* __restrict__ tdw, const float* __restrict__ tdb,
    const float* __restrict__ cw, const float* __restrict__ cb,
    const float* __restrict__ sh, unsigned short* __restrict__ mem)
{
  __shared__ float imgS[8192];    // [c][hw]
  __shared__ float cwgT[1024];    // [c][d] = cw[d][c]*gate[c]
  __shared__ float tarS[160];
  __shared__ float gateS[32];
  const int bid = blockIdx.x;
  const int n = bid & 7, tb = bid >> 3;
  const int hw = threadIdx.x;

  if(hw < 145) tarS[hw] = tar[tb*TAR_ + hw];
  for(int i = hw; i < 8192; i += 256)
    imgS[i] = img[(size_t)tb*8192 + i];
  __syncthreads();
  if(hw < 32){
    float a = tdb[n*32 + hw];
    const float* tw = tdw + (size_t)(n*32 + hw)*273;
    #pragma unroll 5
    for(int x = 0; x < 145; ++x) a += tarS[x]*tw[x];
    gateS[hw] = sigf(a);
  }
  __syncthreads();
  for(int i = hw; i < 1024; i += 256){
    const int c = i >> 5, d = i & 31;
    cwgT[i] = cw[d*32 + c] * gateS[c];
  }
  __syncthreads();

  f32x4 acc[8];
  #pragma unroll
  for(int dq = 0; dq < 8; ++dq){
    const f32x4u cv = *(const f32x4u*)&cb[dq*4];
    acc[dq].x = cv.x; acc[dq].y = cv.y; acc[dq].z = cv.z; acc[dq].w = cv.w;
  }
  #pragma unroll 4
  for(int c = 0; c < 32; ++c){
    const float iv = imgS[c*256 + hw];
    #pragma unroll
    for(int dq = 0; dq < 8; ++dq){
      const f32x4 w = *(const f32x4*)&cwgT[c*32 + dq*4];
      acc[dq].x += iv*w.x; acc[dq].y += iv*w.y;
      acc[dq].z += iv*w.z; acc[dq].w += iv*w.w;
    }
  }
  unsigned short* mrow = mem + (size_t)(n*128 + tb)*AK;
  #pragma unroll
  for(int dq = 0; dq < 8; ++dq){
    mrow[(dq*4 + 0)*256 + hw] = f2bf(acc[dq].x);
    mrow[(dq*4 + 1)*256 + hw] = f2bf(acc[dq].y);
    mrow[(dq*4 + 2)*256 + hw] = f2bf(acc[dq].z);
    mrow[(dq*4 + 3)*256 + hw] = f2bf(acc[dq].w);
  }
  for(int i = hw; i < 320; i += 256){
    if(i < 128)      mrow[8192 + i]       = f2bf(sh[i]);
    else if(i < 273) mrow[8320 + i - 128] = f2bf(tarS[i - 128]);
    else             mrow[8465 + i - 273] = 0;   // zeros to 8512
  }
}

// ---------------------------------------------------------------------------
// MFMA GEMM v5x: round-9-verified gemm5, ONLY change = 1-D grid with
// n = bid&7 (T1 XCD pinning).  XCD i owns schema i: its 2.18MB A panel is
// L2-resident locally (was cross-XCD at 128x re-read = the ~27TB/s L2 wall).
// Double-buffered LDS via global_load_lds, counted vmcnt(8).
// C/D: col=lane&15, row=(lane>>4)*4+j.
// ---------------------------------------------------------------------------
__global__ __launch_bounds__(256) void k_gemm5x(
    const unsigned short* __restrict__ mem, const float* __restrict__ Wih,
    float* __restrict__ xg4)
{
  __shared__ unsigned short Abuf[2][128*64];
  __shared__ float          Bbuf[2][16*64];
  const int bid = blockIdx.x;
  const int n = bid & 7;
  const int r2 = bid >> 3;
  const int gt = r2 & 31, ks = r2 >> 5;
  const int tid = threadIdx.x;
  const int wv = tid >> 6, ln = tid & 63;
  const int lr = ln & 15, lg = ln >> 4;
  const int g0 = gt*16;
  const int kbeg = (ks == 0) ? 0 : 2176 + (ks - 1)*2112;
  const int nsteps = (ks == 0) ? 34 : 33;
  const unsigned short* An = mem + (size_t)n*128*AK;
  const float* Bn = Wih + (size_t)(n*G4H + g0)*MEMIN;

#define STAGE5(bb, kk) do{                                                     \
    _Pragma("unroll")                                                          \
    for(int i_ = 0; i_ < 4; ++i_){                                             \
      const int ci_ = i_*256 + tid;                                            \
      const int row_ = ci_ >> 3;                                               \
      const unsigned short* src_ = An + (size_t)row_*AK + (kk)                 \
                                   + (((ci_ & 7) ^ (row_ & 7)) << 3);          \
      gl_lds16(src_, &Abuf[bb][(i_*256 + wv*64)*8]);                           \
    }                                                                          \
    _Pragma("unroll")                                                          \
    for(int q_ = 0; q_ < 4; ++q_){                                             \
      const int idx_ = q_*256 + tid;                                           \
      const int g_ = idx_ >> 6;                                                \
      const int kd_ = idx_ & 63;                                               \
      const float* srcB_ = Bn + (size_t)g_*MEMIN + (kk)                        \
                           + ((((kd_ >> 3) ^ (g_ & 7)) << 3) + (kd_ & 7));     \
      gl_lds4(srcB_, &Bbuf[bb][q_*256 + wv*64]);                               \
    }                                                                          \
  }while(0)

  f32x4 acc0 = {0.f,0.f,0.f,0.f};
  f32x4 acc1 = {0.f,0.f,0.f,0.f};

  STAGE5(0, kbeg);
  if(nsteps > 1) STAGE5(1, kbeg + KSTEP);

  int b = 0;
  for(int t = 0; t < nsteps; ++t){
    if(t < nsteps - 1){
      asm volatile("s_waitcnt vmcnt(8)" ::: "memory");
    } else {
      asm volatile("s_waitcnt vmcnt(0)" ::: "memory");
    }
    __builtin_amdgcn_s_barrier();
    #pragma unroll
    for(int s = 0; s < 2; ++s){
      const int jb = (s*4 + lg) ^ (lr & 7);
      const float* bp = &Bbuf[b][lr*64 + jb*8];
      const f32x4 blo = *(const f32x4*)bp;
      const f32x4 bhi = *(const f32x4*)(bp + 4);
      short8v bf;
      unsigned* u = (unsigned*)&bf;
      u[0] = pkbf(blo.x, blo.y); u[1] = pkbf(blo.z, blo.w);
      u[2] = pkbf(bhi.x, bhi.y); u[3] = pkbf(bhi.z, bhi.w);
      const short8v a0 = *(const short8v*)&Abuf[b][(wv*32 + lr)*64 + jb*8];
      const short8v a1 = *(const short8v*)&Abuf[b][(wv*32 + 16 + lr)*64 + jb*8];
      acc0 = __builtin_amdgcn_mfma_f32_16x16x32_bf16(a0, bf, acc0, 0, 0, 0);
      acc1 = __builtin_amdgcn_mfma_f32_16x16x32_bf16(a1, bf, acc1, 0, 0, 0);
    }
    __builtin_amdgcn_s_barrier();
    if(t + 2 < nsteps) STAGE5(b, kbeg + (t+2)*KSTEP);
    b ^= 1;
  }
#undef STAGE5

  float* dst = xg4 + (size_t)ks*XGN;
  const int c0 = g0 + lr;
  const int r0 = wv*32 + lg*4, r1 = r0 + 16;
  #pragma unroll
  for(int j = 0; j < 4; ++j){
    dst[(size_t)((r0 + j)*8 + n)*G4H + c0] = acc0[j];
    dst[(size_t)((r1 + j)*8 + n)*G4H + c0] = acc1[j];
  }
}

// ---------------------------------------------------------------------------
// LSTM v2: 64 blocks = (b,n) pairs, 512 threads = gate-row g.  nsum = number
// of K-split partial buffers to sum.
// ---------------------------------------------------------------------------
__global__ __launch_bounds__(512) void k_lstm2(
    const float* __restrict__ xg4, int nsum, const float* __restrict__ Whh,
    const float* __restrict__ bih, const float* __restrict__ bhh,
    float* __restrict__ out)
{
  __shared__ float hS[128];
  __shared__ float preS[512];
  const int bn = blockIdx.x;
  const int n = bn & 7, b = bn >> 3;
  const int g = threadIdx.x;

  unsigned wr[64];
  const float* wrow = Whh + (size_t)(n*G4H + g)*H_;
  #pragma unroll
  for(int i = 0; i < 32; ++i){
    const f32x4 w = *(const f32x4*)(wrow + i*4);
    wr[2*i]   = pkbf(w.x, w.y);
    wr[2*i+1] = pkbf(w.z, w.w);
  }
  const float bias = bih[n*G4H + g] + bhh[n*G4H + g];
  if(g < 128) hS[g] = 0.f;
  float cc = 0.f;
  __syncthreads();

  for(int t = 0; t < 16; ++t){
    const size_t xb = (size_t)((t*8 + b)*8 + n)*G4H + g;
    float acc = bias;
    for(int u = 0; u < nsum; ++u) acc += xg4[xb + (size_t)u*XGN];
    #pragma unroll
    for(int q = 0; q < 32; ++q){
      const f32x4 hv = *(const f32x4*)&hS[q*4];
      const unsigned w0 = wr[2*q], w1 = wr[2*q+1];
      acc += hv.x*bflo(w0) + hv.y*bfhi(w0) + hv.z*bflo(w1) + hv.w*bfhi(w1);
    }
    preS[g] = acc;
    __syncthreads();
    if(g < 128){
      const float iv = sigf(preS[g]);
      const float fv = sigf(preS[128 + g]);
      const float gv = tanhf(preS[256 + g]);
      const float ov = sigf(preS[384 + g]);
      cc = fv*cc + iv*gv;
      const float hn = ov*tanhf(cc);
      hS[g] = hn;
      out[(t*8 + b)*1024 + n*128 + g] = hn;
      if(t == 15){
        out[131072 + (b*8 + n)*128 + g] = hn;   // hT
        out[139264 + (b*8 + n)*128 + g] = cc;   // cT
      }
    }
    __syncthreads();
  }
}

// ---------------------------------------------------------------------------
extern "C" void kernel_launch(void* const* d_in, const int* in_sizes, int n_in,
                              void* d_out, int out_size, void* d_ws, size_t ws_size,
                              hipStream_t stream)
{
  (void)in_sizes; (void)n_in; (void)out_size; (void)ws_size;
  const float* img  = (const float*)d_in[0];
  const float* tar  = (const float*)d_in[1];
  const float* WvB  = (const float*)d_in[7];
  const float* WoW  = (const float*)d_in[8];
  const float* WoB  = (const float*)d_in[9];
  const float* tdw  = (const float*)d_in[10];
  const float* tdb  = (const float*)d_in[11];
  const float* cw   = (const float*)d_in[12];
  const float* cb   = (const float*)d_in[13];
  const float* Wih  = (const float*)d_in[14];
  const float* Whh  = (const float*)d_in[15];
  const float* bih  = (const float*)d_in[16];
  const float* bhh  = (const float*)d_in[17];

  float* wsf = (float*)d_ws;
  float* shw = wsf + 32768;                 // 128 f (gate slot now unused)
  float* xgw = wsf + 32896;                 // 4 x 524288 f
  unsigned short* memA = (unsigned short*)((char*)d_ws + 8520192);   // 17.4 MB

  k_shared<<<128, 64, 0, stream>>>(WvB, WoW, WoB, shw);
  k_conv3<<<1024, 256, 0, stream>>>(img, tar, tdw, tdb, cw, cb, shw, memA);
  k_gemm5x<<<1024, 256, 0, stream>>>(memA, Wih, xgw);
  k_lstm2<<<64, 512, 0, stream>>>(xgw, 4, Whh, bih, bhh, (float*)d_out);
}